// Round 1
// 293.630 us; speedup vs baseline: 1.0201x; 1.0201x over previous
//
#include <hip/hip_runtime.h>
#include <stdint.h>
#include <stddef.h>

#define B_ 8
#define S_ 2048
#define D_ 512
#define QT 64            // q rows per block
#define KTL 32           // keys per iter
#define NIT (S_ / KTL)   // 64

typedef __attribute__((ext_vector_type(8))) short short8;   // 8 x bf16 MFMA frag
typedef __attribute__((ext_vector_type(4))) float f32x4;    // MFMA accum

// ---- LDS layout (bytes), 78592 total; one 8-wave block per CU ----
#define OFF_K0  0         // K tile buf0: 32 keys x 1024B bf16, chunk-swizzled
#define OFF_K1  32768     // FAST: K tile buf1 (double buffer); SLOW: V natural [32 key][1024B]
#define OFF_ST  65536     // S^T fp32 [32 key][256B = 16 chunks], xblk-swizzled
#define OFF_P   73728     // P bf16 [64 q][64B]
#define OFF_A   77824     // 64 f32 alpha
#define OFF_L   78080     // 64 f32 l
#define OFF_M   78336     // 64 u32 packed mask bits for this batch
#define LDS_BYTES 78592

__device__ __forceinline__ void gl_lds16(const void* g, void* l) {
  __builtin_amdgcn_global_load_lds(
      (const __attribute__((address_space(1))) uint32_t*)g,
      (__attribute__((address_space(3))) uint32_t*)l, 16, 0, 0);
}

// CK-style cheap barrier: order LDS only, leave vmem (DMA/prefetch) in flight.
__device__ __forceinline__ void bar_lgkm() {
  __asm__ __volatile__("" ::: "memory");
  __builtin_amdgcn_s_waitcnt(0xC07F);          // lgkmcnt(0), vmcnt(63), expcnt(7)
  __builtin_amdgcn_s_barrier();
  __asm__ __volatile__("" ::: "memory");
}
// Iter-top barrier: also drain vmem (the only outstanding vmem here is the
// K-DMA issued a full iteration ago -> near-zero actual wait).
__device__ __forceinline__ void bar_vm0() {
  __asm__ __volatile__("" ::: "memory");
  __builtin_amdgcn_s_waitcnt(0x0070);          // vmcnt(0), lgkmcnt(0), expcnt(7)
  __builtin_amdgcn_s_barrier();
  __asm__ __volatile__("" ::: "memory");
}

__device__ __forceinline__ uint32_t f2bf(float f) {
  union { float f; uint32_t u; } x; x.f = f;
  uint32_t r = x.u + 0x7FFFu + ((x.u >> 16) & 1u);  // RNE, finite inputs only
  return r >> 16;
}

// fp32 N(0,1): exponent field in [~90,130] (or 0); packed-bf16 read as u32 -> ~200+.
__device__ __forceinline__ bool sniff_fp32(const void* p) {
  const uint32_t* w = (const uint32_t*)p;
  bool ok = true;
  #pragma unroll 1
  for (int i = 0; i < 64; ++i) {
    uint32_t e = (w[i] >> 23) & 0xFFu;
    if (!(e == 0u || (e >= 64u && e <= 192u))) ok = false;
  }
  return ok;
}

__device__ __forceinline__ short8 cvt8(const void* src, bool fp32) {
  short8 d;
  if (fp32) {
    const float* s = (const float*)src;
    f32x4 a = *(const f32x4*)s, c = *(const f32x4*)(s + 4);
    #pragma unroll
    for (int j = 0; j < 4; ++j) { d[j] = (short)f2bf(a[j]); d[4 + j] = (short)f2bf(c[j]); }
  } else {
    d = *(const short8*)src;
  }
  return d;
}

// ---------- merged prep: K -> bf16 (same layout) + V -> V^T bf16 ----------
// grid (32 keytiles-of-64, 8 dvtiles-of-64, 8 batch), 512 threads
//
// V-transpose is LDS-staged (was a strided register gather = 8 scalar
// 2KB-strided fp32 loads/thread -> ~120us dispatch):
//   1) coalesced 32B row loads -> bf16 regs
//   2) dword writes into [64 key][32 word] LDS tile, word slot rotated by
//      (c + key) & 31 so both write (row-major) and read (col-major) phases
//      are <=2-way bank conflicts (2-way is free on gfx950)
//   3) column reads (8x ds_read_u16) -> short8 -> coalesced 16B global store
// Output layout identical to previous version; attn_kernel unchanged.
__global__ void prep_kernel(const void* __restrict__ K, const void* __restrict__ V,
                            uint16_t* __restrict__ kbf, uint16_t* __restrict__ vt) {
  __shared__ uint32_t vtile[64 * 32];   // 8 KiB: [key][32 rotated dwords] = 64x64 bf16
  bool fp32 = sniff_fp32(K);
  int kt = blockIdx.x, dt = blockIdx.y, b = blockIdx.z;
  int t  = threadIdx.x;
  // K convert: rows kt*64 + (t>>3), cols dt*64 + (t&7)*8 .. +8   (coalesced)
  {
    size_t off = (size_t)b * S_ * D_ + (size_t)(kt * 64 + (t >> 3)) * D_ + dt * 64 + (t & 7) * 8;
    const void* src = fp32 ? (const void*)((const float*)K + off)
                           : (const void*)((const uint16_t*)K + off);
    *(short8*)(kbf + off) = cvt8(src, fp32);
  }
  // V stage: coalesced row load, convert, rotated LDS write
  {
    int key = t >> 3;                 // tile-local key row 0..63
    int c0  = (t & 7) * 4;            // first dword column (8 bf16 = 4 dwords)
    size_t off = (size_t)b * S_ * D_ + (size_t)(kt * 64 + key) * D_ + dt * 64 + (t & 7) * 8;
    const void* src = fp32 ? (const void*)((const float*)V + off)
                           : (const void*)((const uint16_t*)V + off);
    short8 d = cvt8(src, fp32);
    const uint32_t* dw = (const uint32_t*)&d;     // dw[i] = bf16 pair (dv = 2(c0+i), 2(c0+i)+1)
    #pragma unroll
    for (int i = 0; i < 4; ++i)
      vtile[key * 32 + ((c0 + i + key) & 31)] = dw[i];
  }
  __syncthreads();
  // V transposed read: thread t -> dv = t>>3, key octet kg = t&7 (coalesced store)
  {
    int dvl = t >> 3;
    int kg  = t & 7;
    short8 o;
    #pragma unroll
    for (int j = 0; j < 8; ++j) {
      int key = kg * 8 + j;
      uint32_t wv = vtile[key * 32 + (((dvl >> 1) + key) & 31)];
      o[j] = (short)((dvl & 1) ? (wv >> 16) : (wv & 0xFFFFu));
    }
    *(short8*)(vt + ((size_t)b * D_ + dt * 64 + dvl) * S_ + kt * 64 + kg * 8) = o;
  }
}

// ---------- FAST K staging: 8 waves x 4 rows, global_load_lds width 16 ----------
__device__ __forceinline__ void stage_K(char* buf, const uint16_t* kg, int w, int lane, int kt) {
  #pragma unroll
  for (int p = 0; p < 4; ++p) {
    int n = p * 8 + w;                               // key row 0..31
    int g = (lane & ~7) | ((lane ^ n) & 7);          // slot s holds chunk (s&~7)|((s^n)&7)
    gl_lds16(kg + ((size_t)(kt * KTL + n)) * D_ + g * 8, buf + n * 1024);
  }
}
// ---------- SLOW staging (convert through registers) ----------
__device__ __forceinline__ void stage_K_slow(char* buf, const void* kg, bool fp32,
                                             int w, int lane, int kt) {
  #pragma unroll
  for (int p = 0; p < 4; ++p) {
    int n = p * 8 + w;
    size_t off = ((size_t)(kt * KTL + n)) * D_ + lane * 8;
    const void* src = fp32 ? (const void*)((const float*)kg + off)
                           : (const void*)((const uint16_t*)kg + off);
    short8 d = cvt8(src, fp32);
    int s = (lane & ~7) | ((lane ^ n) & 7);
    *(short8*)(buf + n * 1024 + s * 16) = d;
  }
}
__device__ __forceinline__ void stage_V_slow(char* smem, const void* vg, bool fp32,
                                             int w, int lane, int kt) {
  #pragma unroll
  for (int p = 0; p < 4; ++p) {
    int n = p * 8 + w;
    size_t off = ((size_t)(kt * KTL + n)) * D_ + lane * 8;
    const void* src = fp32 ? (const void*)((const float*)vg + off)
                           : (const void*)((const uint16_t*)vg + off);
    short8 d = cvt8(src, fp32);
    *(short8*)(smem + OFF_K1 + n * 1024 + lane * 16) = d;   // natural layout
  }
}

// ---------- flash attention: 64-q tile, 8 waves, 1 block/CU ----------
template<bool FAST>
__global__ __launch_bounds__(512, 2)
void attn_kernel(const void* __restrict__ Q, const void* __restrict__ K,
                 const void* __restrict__ V, const void* __restrict__ mask,
                 const uint16_t* __restrict__ kbf, const uint16_t* __restrict__ vtbf,
                 void* __restrict__ out) {
  extern __shared__ char smem[];
  const int tid  = threadIdx.x;
  const int lane = tid & 63;
  const int w    = tid >> 6;          // wave 0..7
  const int m15  = lane & 15;
  const int kq   = lane >> 4;

  const bool fp32 = sniff_fp32(Q);

  const int b     = blockIdx.x;       // batch; linear%8 == XCD -> per-batch L2 residency
  const int qbase = blockIdx.y * QT;
  const int qt_w  = w >> 1;           // QK q-tile 0..3 (16 rows)
  const int kh    = w & 1;            // QK key half

  const uint16_t* kgf  = FAST ? (kbf + (size_t)b * S_ * D_) : nullptr;
  const uint16_t* vtg  = FAST ? (vtbf + (size_t)b * D_ * S_) : nullptr;
  const void* kgs = fp32 ? (const void*)((const float*)K + (size_t)b * S_ * D_)
                         : (const void*)((const uint16_t*)K + (size_t)b * S_ * D_);
  const void* vgs = fp32 ? (const void*)((const float*)V + (size_t)b * S_ * D_)
                         : (const void*)((const uint16_t*)V + (size_t)b * S_ * D_);

  // ---- pack this batch's key mask into 64 LDS words (dtype auto-detect) ----
  if (tid < 64) {
    const uint32_t* mw = (const uint32_t*)mask;
    const uint8_t*  mb = (const uint8_t*)mask;
    bool is64 = true, any_even = false, is32 = true;
    for (int j = 0; j < 64; ++j) {
      uint32_t lo = mw[2 * j], hi = mw[2 * j + 1];
      if (hi != 0u || lo > 1u) is64 = false;
      if (lo) any_even = true;
    }
    is64 = is64 && any_even;
    for (int j = 0; j < 128; ++j) {
      uint32_t x = mw[j];
      if (x != 0u && x != 1u && x != 0x3F800000u) is32 = false;
    }
    uint32_t bits = 0;
    int base = b * S_ + tid * 32;
    for (int e = 0; e < 32; ++e) {
      uint32_t x = is64 ? mw[2 * (base + e)]
                        : (is32 ? mw[base + e] : (uint32_t)mb[base + e]);
      bits |= (x ? 1u : 0u) << e;
    }
    *(uint32_t*)(smem + OFF_M + tid * 4) = bits;
  }

  // ---- Q fragments resident in registers (A-layout = row-major) ----
  short8 aq[16];
  {
    size_t q0 = ((size_t)b * S_ + qbase + qt_w * 16 + m15) * D_ + kq * 8;
    #pragma unroll
    for (int sl = 0; sl < 16; ++sl) {
      size_t off = q0 + sl * 32;
      const void* src = fp32 ? (const void*)((const float*)Q + off)
                             : (const void*)((const uint16_t*)Q + off);
      aq[sl] = cvt8(src, fp32);
    }
  }

  f32x4 acc_o[4][4];                  // 64 q rows x wave dv slice [w*64, w*64+64)
  #pragma unroll
  for (int i = 0; i < 4; ++i)
    #pragma unroll
    for (int j = 0; j < 4; ++j)
      acc_o[i][j] = (f32x4){0.f, 0.f, 0.f, 0.f};

  float m_run = -1e30f, l_run = 0.f;
  const float k1 = 0.06375872f;       // log2(e)/sqrt(512); exp2-domain softmax

  if (FAST) stage_K(smem + OFF_K0, kgf, w, lane, 0);

  for (int kt = 0; kt < NIT; ++kt) {
    char* kbuf = smem + ((kt & 1) && FAST ? OFF_K1 : OFF_K0);
    if (FAST) {
      bar_vm0();                      // B1: K[kt] DMA (issued 1 iter ago) landed
    } else {
      __syncthreads();                // readers of previous tiles done
      stage_K_slow(smem + OFF_K0, kgs, fp32, w, lane, kt);
      stage_V_slow(smem, vgs, fp32, w, lane, kt);
      __syncthreads();
    }

    // V fragments for THIS iter: direct global -> regs (no LDS, no reuse lost)
    short8 vf[4];
    if (FAST) {
      #pragma unroll
      for (int ct = 0; ct < 4; ++ct)
        vf[ct] = *(const short8*)(vtg + (size_t)(w * 64 + ct * 16 + m15) * S_
                                  + kt * KTL + kq * 8);
      if (kt < NIT - 1)               // prefetch next K tile into other buffer
        stage_K(smem + ((kt & 1) ? OFF_K0 : OFF_K1), kgf, w, lane, kt + 1);
    }

    int keyg = kt * KTL + kh * 16 + m15;
    float bv = ((*(const uint32_t*)(smem + OFF_M + (keyg >> 5) * 4) >> (keyg & 31)) & 1u)
               ? -3.0e38f : 0.f;

    // ---- QK^T: wave does 16q x 16k tile; Q regs, K B-frags from LDS ----
    f32x4 acc_s = (f32x4){0.f, 0.f, 0.f, 0.f};
    #pragma unroll
    for (int sl = 0; sl < 16; ++sl) {
      int n  = kh * 16 + m15;
      int c  = sl * 4 + kq;
      int cs = (c & ~7) | ((c ^ n) & 7);
      short8 bf = *(const short8*)(kbuf + n * 1024 + cs * 16);
      acc_s = __builtin_amdgcn_mfma_f32_16x16x32_bf16(aq[sl], bf, acc_s, 0, 0, 0);
    }

    // ---- S^T fp32 (exp2-domain, bias folded); xblk has key bits 0..4 ----
    {
      int key  = kh * 16 + m15;
      int blk  = qt_w * 4 + kq;                       // q>>2
      int xblk = blk ^ (key & 15) ^ ((key >> 2) & 3);
      f32x4 sv;
      #pragma unroll
      for (int r = 0; r < 4; ++r) sv[r] = acc_s[r] * k1 + bv;
      *(f32x4*)(smem + OFF_ST + key * 256 + xblk * 16) = sv;
    }
    bar_lgkm();                        // B2: S^T visible (LDS-only wait)

    // ---- online softmax: row r = w*8+(lane>>3); 8 lanes cover 32 keys ----
    {
      int r  = w * 8 + (lane >> 3);
      int k0 = (lane & 7) * 4;
      float u[4];
      #pragma unroll
      for (int i = 0; i < 4; ++i) {
        int k    = k0 + i;
        int xblk = (r >> 2) ^ (k & 15) ^ ((k >> 2) & 3);
        u[i] = *(const float*)(smem + OFF_ST + k * 256 + xblk * 16 + (r & 3) * 4);
      }
      float mt = fmaxf(fmaxf(u[0], u[1]), fmaxf(u[2], u[3]));
      mt = fmaxf(mt, __shfl_xor(mt, 1, 64));
      mt = fmaxf(mt, __shfl_xor(mt, 2, 64));
      mt = fmaxf(mt, __shfl_xor(mt, 4, 64));
      float m_new = fmaxf(m_run, mt);
      float alpha = exp2f(m_run - m_new);
      float s = 0.f;
      #pragma unroll
      for (int i = 0; i < 4; ++i) { u[i] = exp2f(u[i] - m_new); s += u[i]; }
      s += __shfl_xor(s, 1, 64);
      s += __shfl_xor(s, 2, 64);
      s += __shfl_xor(s, 4, 64);
      l_run = l_run * alpha + s;
      m_run = m_new;
      uint2 d;
      d.x = f2bf(u[0]) | (f2bf(u[1]) << 16);
      d.y = f2bf(u[2]) | (f2bf(u[3]) << 16);
      *(uint2*)(smem + OFF_P + r * 64 + k0 * 2) = d;
      if ((lane & 7) == 0) {
        *(float*)(smem + OFF_A + r * 4) = alpha;
        *(float*)(smem + OFF_L + r * 4) = l_run;
      }
    }
    bar_lgkm();                        // B3: P/alpha/l visible (LDS-only wait)

    // ---- PV: all 64 q rows x wave's 64-dv slice ----
    #pragma unroll
    for (int rt = 0; rt < 4; ++rt) {
      f32x4 al = *(const f32x4*)(smem + OFF_A + (rt * 16 + kq * 4) * 4);
      #pragma unroll
      for (int ct = 0; ct < 4; ++ct) acc_o[rt][ct] *= al;
    }
    short8 ap[4];
    #pragma unroll
    for (int rt = 0; rt < 4; ++rt)
      ap[rt] = *(const short8*)(smem + OFF_P + (rt * 16 + m15) * 64 + kq * 16);
    #pragma unroll
    for (int ct = 0; ct < 4; ++ct) {
      short8 bvv;
      if (FAST) {
        bvv = vf[ct];
      } else {
        #pragma unroll
        for (int j = 0; j < 8; ++j)
          bvv[j] = *(const short*)(smem + OFF_K1 + (kq * 8 + j) * 1024
                                   + (w * 64 + ct * 16 + m15) * 2);
      }
      #pragma unroll
      for (int rt = 0; rt < 4; ++rt)
        acc_o[rt][ct] = __builtin_amdgcn_mfma_f32_16x16x32_bf16(
            ap[rt], bvv, acc_o[rt][ct], 0, 0, 0);
    }
  }

  // ---- epilogue: O /= l (guarded), store in input dtype ----
  #pragma unroll
  for (int rt = 0; rt < 4; ++rt) {
    f32x4 lv = *(const f32x4*)(smem + OFF_L + (rt * 16 + kq * 4) * 4);
    f32x4 inv;
    #pragma unroll
    for (int r = 0; r < 4; ++r) inv[r] = lv[r] > 0.f ? 1.f / lv[r] : 0.f;
    #pragma unroll
    for (int ct = 0; ct < 4; ++ct) {
      int col = w * 64 + ct * 16 + m15;
      #pragma unroll
      for (int r = 0; r < 4; ++r) {
        int row = qbase + rt * 16 + kq * 4 + r;
        size_t idx = ((size_t)b * S_ + row) * D_ + col;
        float val = acc_o[rt][ct][r] * inv[r];
        if (fp32) ((float*)out)[idx] = val;
        else      ((uint16_t*)out)[idx] = (uint16_t)f2bf(val);
      }
    }
  }
}

extern "C" void kernel_launch(void* const* d_in, const int* in_sizes, int n_in,
                              void* d_out, int out_size, void* d_ws, size_t ws_size,
                              hipStream_t stream) {
  (void)in_sizes; (void)n_in; (void)out_size;
  const void* Q    = d_in[0];
  const void* K    = d_in[1];
  const void* V    = d_in[2];
  const void* mask = d_in[3];

  const size_t half = (size_t)B_ * S_ * D_ * 2;     // 16 MiB per bf16 buffer
  bool fast = ws_size >= 2 * half;

  if (fast) {
    uint16_t* kbf  = (uint16_t*)d_ws;
    uint16_t* vtbf = (uint16_t*)((char*)d_ws + half);
    prep_kernel<<<dim3(32, 8, 8), 512, 0, stream>>>(K, V, kbf, vtbf);
    hipFuncSetAttribute((const void*)attn_kernel<true>,
                        hipFuncAttributeMaxDynamicSharedMemorySize, LDS_BYTES);
    attn_kernel<true><<<dim3(8, S_ / QT), 512, LDS_BYTES, stream>>>(
        Q, K, V, mask, kbf, vtbf, d_out);
  } else {
    hipFuncSetAttribute((const void*)attn_kernel<false>,
                        hipFuncAttributeMaxDynamicSharedMemorySize, LDS_BYTES);
    attn_kernel<false><<<dim3(8, S_ / QT), 512, LDS_BYTES, stream>>>(
        Q, K, V, mask, nullptr, nullptr, d_out);
  }
}

// Round 2
// 280.215 us; speedup vs baseline: 1.0689x; 1.0479x over previous
//
#include <hip/hip_runtime.h>
#include <stdint.h>
#include <stddef.h>

#define B_ 8
#define S_ 2048
#define D_ 512
#define QT 64            // q rows per block
#define KTL 64           // keys per barrier cycle (was 32)
#define NIT (S_ / KTL)   // 32

typedef __attribute__((ext_vector_type(8))) short short8;   // 8 x bf16 MFMA frag
typedef __attribute__((ext_vector_type(4))) float f32x4;    // MFMA accum

// ---- LDS layout (bytes), 156416 total; one 8-wave block per CU ----
#define OFF_K0  0         // K tile buf0: 64 keys x 1024B bf16, chunk-swizzled
#define OFF_K1  65536     // FAST: K tile buf1 (double buffer); SLOW: V natural [64 key][1024B]
#define OFF_ST  131072    // S^T fp32 [64 key][256B = 16 chunks], xblk-swizzled
#define OFF_P   147456    // P bf16 [64 q][128B = 8 granules of 16B], granule-swizzled
#define OFF_A   155648    // 64 f32 alpha
#define OFF_L   155904    // 64 f32 l
#define OFF_M   156160    // 64 u32 packed mask bits for this batch
#define LDS_BYTES 156416

__device__ __forceinline__ void gl_lds16(const void* g, void* l) {
  __builtin_amdgcn_global_load_lds(
      (const __attribute__((address_space(1))) uint32_t*)g,
      (__attribute__((address_space(3))) uint32_t*)l, 16, 0, 0);
}

// CK-style cheap barrier: order LDS only, leave vmem (DMA/prefetch) in flight.
__device__ __forceinline__ void bar_lgkm() {
  __asm__ __volatile__("" ::: "memory");
  __builtin_amdgcn_s_waitcnt(0xC07F);          // lgkmcnt(0), vmcnt(63), expcnt(7)
  __builtin_amdgcn_s_barrier();
  __asm__ __volatile__("" ::: "memory");
}
// Iter-top barrier: also drain vmem (the only outstanding vmem here is the
// K-DMA issued a full iteration ago -> near-zero actual wait).
__device__ __forceinline__ void bar_vm0() {
  __asm__ __volatile__("" ::: "memory");
  __builtin_amdgcn_s_waitcnt(0x0070);          // vmcnt(0), lgkmcnt(0), expcnt(7)
  __builtin_amdgcn_s_barrier();
  __asm__ __volatile__("" ::: "memory");
}

__device__ __forceinline__ uint32_t f2bf(float f) {
  union { float f; uint32_t u; } x; x.f = f;
  uint32_t r = x.u + 0x7FFFu + ((x.u >> 16) & 1u);  // RNE, finite inputs only
  return r >> 16;
}

// fp32 N(0,1): exponent field in [~90,130] (or 0); packed-bf16 read as u32 -> ~200+.
__device__ __forceinline__ bool sniff_fp32(const void* p) {
  const uint32_t* w = (const uint32_t*)p;
  bool ok = true;
  #pragma unroll 1
  for (int i = 0; i < 64; ++i) {
    uint32_t e = (w[i] >> 23) & 0xFFu;
    if (!(e == 0u || (e >= 64u && e <= 192u))) ok = false;
  }
  return ok;
}

__device__ __forceinline__ short8 cvt8(const void* src, bool fp32) {
  short8 d;
  if (fp32) {
    const float* s = (const float*)src;
    f32x4 a = *(const f32x4*)s, c = *(const f32x4*)(s + 4);
    #pragma unroll
    for (int j = 0; j < 4; ++j) { d[j] = (short)f2bf(a[j]); d[4 + j] = (short)f2bf(c[j]); }
  } else {
    d = *(const short8*)src;
  }
  return d;
}

// ---------- merged prep: K -> bf16 (same layout) + V -> V^T bf16 ----------
// grid (32 keytiles-of-64, 8 dvtiles-of-64, 8 batch), 512 threads
__global__ void prep_kernel(const void* __restrict__ K, const void* __restrict__ V,
                            uint16_t* __restrict__ kbf, uint16_t* __restrict__ vt) {
  __shared__ uint32_t vtile[64 * 32];   // 8 KiB: [key][32 rotated dwords] = 64x64 bf16
  bool fp32 = sniff_fp32(K);
  int kt = blockIdx.x, dt = blockIdx.y, b = blockIdx.z;
  int t  = threadIdx.x;
  // K convert: rows kt*64 + (t>>3), cols dt*64 + (t&7)*8 .. +8   (coalesced)
  {
    size_t off = (size_t)b * S_ * D_ + (size_t)(kt * 64 + (t >> 3)) * D_ + dt * 64 + (t & 7) * 8;
    const void* src = fp32 ? (const void*)((const float*)K + off)
                           : (const void*)((const uint16_t*)K + off);
    *(short8*)(kbf + off) = cvt8(src, fp32);
  }
  // V stage: coalesced row load, convert, rotated LDS write
  {
    int key = t >> 3;                 // tile-local key row 0..63
    int c0  = (t & 7) * 4;            // first dword column (8 bf16 = 4 dwords)
    size_t off = (size_t)b * S_ * D_ + (size_t)(kt * 64 + key) * D_ + dt * 64 + (t & 7) * 8;
    const void* src = fp32 ? (const void*)((const float*)V + off)
                           : (const void*)((const uint16_t*)V + off);
    short8 d = cvt8(src, fp32);
    const uint32_t* dw = (const uint32_t*)&d;
    #pragma unroll
    for (int i = 0; i < 4; ++i)
      vtile[key * 32 + ((c0 + i + key) & 31)] = dw[i];
  }
  __syncthreads();
  // V transposed read: thread t -> dv = t>>3, key octet kg = t&7 (coalesced store)
  {
    int dvl = t >> 3;
    int kg  = t & 7;
    short8 o;
    #pragma unroll
    for (int j = 0; j < 8; ++j) {
      int key = kg * 8 + j;
      uint32_t wv = vtile[key * 32 + (((dvl >> 1) + key) & 31)];
      o[j] = (short)((dvl & 1) ? (wv >> 16) : (wv & 0xFFFFu));
    }
    *(short8*)(vt + ((size_t)b * D_ + dt * 64 + dvl) * S_ + kt * 64 + kg * 8) = o;
  }
}

// ---------- FAST K staging: 8 waves x 8 rows, global_load_lds width 16 ----------
__device__ __forceinline__ void stage_K(char* buf, const uint16_t* kg, int w, int lane, int kt) {
  #pragma unroll
  for (int p = 0; p < 8; ++p) {
    int n = p * 8 + w;                               // key row 0..63
    int g = (lane & ~7) | ((lane ^ n) & 7);          // slot s holds chunk (s&~7)|((s^n)&7)
    gl_lds16(kg + ((size_t)(kt * KTL + n)) * D_ + g * 8, buf + n * 1024);
  }
}
// ---------- SLOW staging (convert through registers) ----------
__device__ __forceinline__ void stage_K_slow(char* buf, const void* kg, bool fp32,
                                             int w, int lane, int kt) {
  #pragma unroll
  for (int p = 0; p < 8; ++p) {
    int n = p * 8 + w;
    size_t off = ((size_t)(kt * KTL + n)) * D_ + lane * 8;
    const void* src = fp32 ? (const void*)((const float*)kg + off)
                           : (const void*)((const uint16_t*)kg + off);
    short8 d = cvt8(src, fp32);
    int s = (lane & ~7) | ((lane ^ n) & 7);
    *(short8*)(buf + n * 1024 + s * 16) = d;
  }
}
__device__ __forceinline__ void stage_V_slow(char* smem, const void* vg, bool fp32,
                                             int w, int lane, int kt) {
  #pragma unroll
  for (int p = 0; p < 8; ++p) {
    int n = p * 8 + w;
    size_t off = ((size_t)(kt * KTL + n)) * D_ + lane * 8;
    const void* src = fp32 ? (const void*)((const float*)vg + off)
                           : (const void*)((const uint16_t*)vg + off);
    short8 d = cvt8(src, fp32);
    *(short8*)(smem + OFF_K1 + n * 1024 + lane * 16) = d;   // natural layout
  }
}

// ---------- flash attention: 64-q tile, 8 waves, 64 keys per barrier cycle ----------
template<bool FAST>
__global__ __launch_bounds__(512, 2)
void attn_kernel(const void* __restrict__ Q, const void* __restrict__ K,
                 const void* __restrict__ V, const void* __restrict__ mask,
                 const uint16_t* __restrict__ kbf, const uint16_t* __restrict__ vtbf,
                 void* __restrict__ out) {
  extern __shared__ char smem[];
  const int tid  = threadIdx.x;
  const int lane = tid & 63;
  const int w    = tid >> 6;          // wave 0..7
  const int m15  = lane & 15;
  const int kq   = lane >> 4;

  const bool fp32 = sniff_fp32(Q);

  const int b     = blockIdx.x;       // batch; linear%8 == XCD -> per-batch L2 residency
  const int qbase = blockIdx.y * QT;
  const int qt    = w >> 1;           // QK q-tile 0..3 (16 rows)
  const int kk0   = (w & 1) * 2;      // first of TWO 16-key slices this wave owns

  const uint16_t* kgf  = FAST ? (kbf + (size_t)b * S_ * D_) : nullptr;
  const uint16_t* vtg  = FAST ? (vtbf + (size_t)b * D_ * S_) : nullptr;
  const void* kgs = fp32 ? (const void*)((const float*)K + (size_t)b * S_ * D_)
                         : (const void*)((const uint16_t*)K + (size_t)b * S_ * D_);
  const void* vgs = fp32 ? (const void*)((const float*)V + (size_t)b * S_ * D_)
                         : (const void*)((const uint16_t*)V + (size_t)b * S_ * D_);

  // ---- pack this batch's key mask into 64 LDS words (dtype auto-detect) ----
  if (tid < 64) {
    const uint32_t* mw = (const uint32_t*)mask;
    const uint8_t*  mb = (const uint8_t*)mask;
    bool is64 = true, any_even = false, is32 = true;
    for (int j = 0; j < 64; ++j) {
      uint32_t lo = mw[2 * j], hi = mw[2 * j + 1];
      if (hi != 0u || lo > 1u) is64 = false;
      if (lo) any_even = true;
    }
    is64 = is64 && any_even;
    for (int j = 0; j < 128; ++j) {
      uint32_t x = mw[j];
      if (x != 0u && x != 1u && x != 0x3F800000u) is32 = false;
    }
    uint32_t bits = 0;
    int base = b * S_ + tid * 32;
    for (int e = 0; e < 32; ++e) {
      uint32_t x = is64 ? mw[2 * (base + e)]
                        : (is32 ? mw[base + e] : (uint32_t)mb[base + e]);
      bits |= (x ? 1u : 0u) << e;
    }
    *(uint32_t*)(smem + OFF_M + tid * 4) = bits;
  }

  // ---- Q fragments resident in registers (A-layout = row-major) ----
  short8 aq[16];
  {
    size_t q0 = ((size_t)b * S_ + qbase + qt * 16 + m15) * D_ + kq * 8;
    #pragma unroll
    for (int sl = 0; sl < 16; ++sl) {
      size_t off = q0 + sl * 32;
      const void* src = fp32 ? (const void*)((const float*)Q + off)
                             : (const void*)((const uint16_t*)Q + off);
      aq[sl] = cvt8(src, fp32);
    }
  }

  f32x4 acc_o[4][4];                  // 64 q rows x wave dv slice [w*64, w*64+64)
  #pragma unroll
  for (int i = 0; i < 4; ++i)
    #pragma unroll
    for (int j = 0; j < 4; ++j)
      acc_o[i][j] = (f32x4){0.f, 0.f, 0.f, 0.f};

  float m_run = -1e30f, l_run = 0.f;
  const float k1 = 0.06375872f;       // log2(e)/sqrt(512); exp2-domain softmax

  if (FAST) stage_K(smem + OFF_K0, kgf, w, lane, 0);

  for (int kt = 0; kt < NIT; ++kt) {
    char* kbuf = smem + ((kt & 1) && FAST ? OFF_K1 : OFF_K0);
    if (FAST) {
      bar_vm0();                      // B1: K[kt] DMA (issued 1 iter ago) landed
    } else {
      __syncthreads();                // readers of previous tiles done
      stage_K_slow(smem + OFF_K0, kgs, fp32, w, lane, kt);
      stage_V_slow(smem, vgs, fp32, w, lane, kt);
      __syncthreads();
    }

    // V fragments for THIS iter: direct global -> regs (L2-resident V^T)
    short8 vf[4][2];
    if (FAST) {
      #pragma unroll
      for (int ct = 0; ct < 4; ++ct)
        #pragma unroll
        for (int kc = 0; kc < 2; ++kc)
          vf[ct][kc] = *(const short8*)(vtg + (size_t)(w * 64 + ct * 16 + m15) * S_
                                        + kt * KTL + kc * 32 + kq * 8);
      if (kt < NIT - 1)               // prefetch next K tile into other buffer
        stage_K(smem + ((kt & 1) ? OFF_K0 : OFF_K1), kgf, w, lane, kt + 1);
    }

    // ---- QK^T: wave does 16q x 32k (two 16k slices, independent MFMA chains) ----
    const int n0 = kk0 * 16 + m15;          // slice-0 key row
    const int n1 = n0 + 16;                 // slice-1 key row
    f32x4 acc_s0 = (f32x4){0.f, 0.f, 0.f, 0.f};
    f32x4 acc_s1 = (f32x4){0.f, 0.f, 0.f, 0.f};
    #pragma unroll
    for (int sl = 0; sl < 16; ++sl) {
      int c   = sl * 4 + kq;
      int cs0 = (c & ~7) | ((c ^ n0) & 7);
      int cs1 = (c & ~7) | ((c ^ n1) & 7);
      short8 b0 = *(const short8*)(kbuf + n0 * 1024 + cs0 * 16);
      short8 b1 = *(const short8*)(kbuf + n1 * 1024 + cs1 * 16);
      acc_s0 = __builtin_amdgcn_mfma_f32_16x16x32_bf16(aq[sl], b0, acc_s0, 0, 0, 0);
      acc_s1 = __builtin_amdgcn_mfma_f32_16x16x32_bf16(aq[sl], b1, acc_s1, 0, 0, 0);
    }

    // ---- S^T fp32 (exp2-domain, bias folded); xblk spreads key bits 0..5 ----
    #pragma unroll
    for (int sli = 0; sli < 2; ++sli) {
      int key  = (sli == 0) ? n0 : n1;
      int keyg = kt * KTL + key;
      float bv = ((*(const uint32_t*)(smem + OFF_M + (keyg >> 5) * 4) >> (keyg & 31)) & 1u)
                 ? -3.0e38f : 0.f;
      int blk  = qt * 4 + kq;                        // q>>2
      int xblk = blk ^ (key & 15) ^ ((key >> 2) & 3) ^ (((key >> 4) & 3) << 1);
      f32x4 sv;
      f32x4 as = (sli == 0) ? acc_s0 : acc_s1;
      #pragma unroll
      for (int r = 0; r < 4; ++r) sv[r] = as[r] * k1 + bv;
      *(f32x4*)(smem + OFF_ST + key * 256 + xblk * 16) = sv;
    }
    bar_lgkm();                        // B2: S^T visible (LDS-only wait)

    // ---- online softmax: row r = w*8+(lane>>3); 8 lanes cover 64 keys ----
    {
      int r  = w * 8 + (lane >> 3);
      int k0 = (lane & 7) * 8;
      float u[8];
      #pragma unroll
      for (int i = 0; i < 8; ++i) {
        int k    = k0 + i;
        int xblk = (r >> 2) ^ (k & 15) ^ ((k >> 2) & 3) ^ (((k >> 4) & 3) << 1);
        u[i] = *(const float*)(smem + OFF_ST + k * 256 + xblk * 16 + (r & 3) * 4);
      }
      float mt = fmaxf(fmaxf(fmaxf(u[0], u[1]), fmaxf(u[2], u[3])),
                       fmaxf(fmaxf(u[4], u[5]), fmaxf(u[6], u[7])));
      mt = fmaxf(mt, __shfl_xor(mt, 1, 64));
      mt = fmaxf(mt, __shfl_xor(mt, 2, 64));
      mt = fmaxf(mt, __shfl_xor(mt, 4, 64));
      float m_new = fmaxf(m_run, mt);
      float alpha = exp2f(m_run - m_new);
      float s = 0.f;
      #pragma unroll
      for (int i = 0; i < 8; ++i) { u[i] = exp2f(u[i] - m_new); s += u[i]; }
      s += __shfl_xor(s, 1, 64);
      s += __shfl_xor(s, 2, 64);
      s += __shfl_xor(s, 4, 64);
      l_run = l_run * alpha + s;
      m_run = m_new;
      uint4 d;
      d.x = f2bf(u[0]) | (f2bf(u[1]) << 16);
      d.y = f2bf(u[2]) | (f2bf(u[3]) << 16);
      d.z = f2bf(u[4]) | (f2bf(u[5]) << 16);
      d.w = f2bf(u[6]) | (f2bf(u[7]) << 16);
      int g = (lane & 7) ^ (r & 7);              // granule swizzle
      *(uint4*)(smem + OFF_P + r * 128 + g * 16) = d;
      if ((lane & 7) == 0) {
        *(float*)(smem + OFF_A + r * 4) = alpha;
        *(float*)(smem + OFF_L + r * 4) = l_run;
      }
    }
    bar_lgkm();                        // B3: P/alpha/l visible (LDS-only wait)

    // ---- PV: all 64 q rows x wave's 64-dv slice, K=64 (two 32-chunks) ----
    #pragma unroll
    for (int rt = 0; rt < 4; ++rt) {
      f32x4 al = *(const f32x4*)(smem + OFF_A + (rt * 16 + kq * 4) * 4);
      #pragma unroll
      for (int ct = 0; ct < 4; ++ct) acc_o[rt][ct] *= al;
    }
    short8 ap[4][2];
    #pragma unroll
    for (int rt = 0; rt < 4; ++rt)
      #pragma unroll
      for (int kc = 0; kc < 2; ++kc) {
        int rr = rt * 16 + m15;
        int g  = (kc * 4 + kq) ^ (rr & 7);       // granule unswizzle
        ap[rt][kc] = *(const short8*)(smem + OFF_P + rr * 128 + g * 16);
      }
    #pragma unroll
    for (int ct = 0; ct < 4; ++ct) {
      #pragma unroll
      for (int kc = 0; kc < 2; ++kc) {
        short8 bvv;
        if (FAST) {
          bvv = vf[ct][kc];
        } else {
          #pragma unroll
          for (int j = 0; j < 8; ++j)
            bvv[j] = *(const short*)(smem + OFF_K1 + (kc * 32 + kq * 8 + j) * 1024
                                     + (w * 64 + ct * 16 + m15) * 2);
        }
        #pragma unroll
        for (int rt = 0; rt < 4; ++rt)
          acc_o[rt][ct] = __builtin_amdgcn_mfma_f32_16x16x32_bf16(
              ap[rt][kc], bvv, acc_o[rt][ct], 0, 0, 0);
      }
    }
  }

  // ---- epilogue: O /= l (guarded), store in input dtype ----
  #pragma unroll
  for (int rt = 0; rt < 4; ++rt) {
    f32x4 lv = *(const f32x4*)(smem + OFF_L + (rt * 16 + kq * 4) * 4);
    f32x4 inv;
    #pragma unroll
    for (int r = 0; r < 4; ++r) inv[r] = lv[r] > 0.f ? 1.f / lv[r] : 0.f;
    #pragma unroll
    for (int ct = 0; ct < 4; ++ct) {
      int col = w * 64 + ct * 16 + m15;
      #pragma unroll
      for (int r = 0; r < 4; ++r) {
        int row = qbase + rt * 16 + kq * 4 + r;
        size_t idx = ((size_t)b * S_ + row) * D_ + col;
        float val = acc_o[rt][ct][r] * inv[r];
        if (fp32) ((float*)out)[idx] = val;
        else      ((uint16_t*)out)[idx] = (uint16_t)f2bf(val);
      }
    }
  }
}

extern "C" void kernel_launch(void* const* d_in, const int* in_sizes, int n_in,
                              void* d_out, int out_size, void* d_ws, size_t ws_size,
                              hipStream_t stream) {
  (void)in_sizes; (void)n_in; (void)out_size;
  const void* Q    = d_in[0];
  const void* K    = d_in[1];
  const void* V    = d_in[2];
  const void* mask = d_in[3];

  const size_t half = (size_t)B_ * S_ * D_ * 2;     // 16 MiB per bf16 buffer
  bool fast = ws_size >= 2 * half;

  if (fast) {
    uint16_t* kbf  = (uint16_t*)d_ws;
    uint16_t* vtbf = (uint16_t*)((char*)d_ws + half);
    prep_kernel<<<dim3(32, 8, 8), 512, 0, stream>>>(K, V, kbf, vtbf);
    hipFuncSetAttribute((const void*)attn_kernel<true>,
                        hipFuncAttributeMaxDynamicSharedMemorySize, LDS_BYTES);
    attn_kernel<true><<<dim3(8, S_ / QT), 512, LDS_BYTES, stream>>>(
        Q, K, V, mask, kbf, vtbf, d_out);
  } else {
    hipFuncSetAttribute((const void*)attn_kernel<false>,
                        hipFuncAttributeMaxDynamicSharedMemorySize, LDS_BYTES);
    attn_kernel<false><<<dim3(8, S_ / QT), 512, LDS_BYTES, stream>>>(
        Q, K, V, mask, nullptr, nullptr, d_out);
  }
}